// Round 1
// 223.570 us; speedup vs baseline: 1.0371x; 1.0371x over previous
//
#include <hip/hip_runtime.h>
#include <stdint.h>

#define N_NODES 50000
#define N_EDGES 800000
#define DIM     128
#define NB   196                 // dst buckets: dst>>8
#define CAP  8192                // fixed slots per bucket in 'packed'
#define CHUNK 2048               // edges per scatter block
#define NBLK 391                 // ceil(800000/2048)
#define GCAP 4096                // LDS edge cap for gather blocks
#define G3CAP 8192               // LDS edge cap for gather3 blocks

typedef __attribute__((ext_vector_type(8))) unsigned short ushort8_t;
typedef __attribute__((ext_vector_type(8))) short bfrag;    // 8 bf16 = 4 VGPR
typedef __attribute__((ext_vector_type(4))) float f32x4;

// ---------------- Threefry-2x32 (exact JAX 20-round) ----------------
__host__ __device__ inline void threefry2x32(uint32_t k0, uint32_t k1,
                                             uint32_t x0, uint32_t x1,
                                             uint32_t& o0, uint32_t& o1) {
    uint32_t ks0 = k0, ks1 = k1, ks2 = k0 ^ k1 ^ 0x1BD11BDAu;
    uint32_t v0 = x0 + ks0, v1 = x1 + ks1;
#define TF_R(r) { v0 += v1; v1 = (v1 << (r)) | (v1 >> (32 - (r))); v1 ^= v0; }
    TF_R(13) TF_R(15) TF_R(26) TF_R(6)
    v0 += ks1; v1 += ks2 + 1u;
    TF_R(17) TF_R(29) TF_R(16) TF_R(24)
    v0 += ks2; v1 += ks0 + 2u;
    TF_R(13) TF_R(15) TF_R(26) TF_R(6)
    v0 += ks0; v1 += ks1 + 3u;
    TF_R(17) TF_R(29) TF_R(16) TF_R(24)
    v0 += ks1; v1 += ks2 + 4u;
    TF_R(13) TF_R(15) TF_R(26) TF_R(6)
    v0 += ks2; v1 += ks0 + 5u;
#undef TF_R
    o0 = v0; o1 = v1;
}

__device__ inline float drop_scale(uint32_t kk0, uint32_t kk1, uint32_t i) {
    uint32_t b0, b1;
    threefry2x32(kk0, kk1, 0u, i, b0, b1);
    uint32_t bits = b0 ^ b1;               // partitionable 32-bit path (verified R0)
    return (bits >> 31) ? 0.0f : 2.0f;     // keep iff u < 0.5 iff top bit 0
}

__device__ inline float bf2f(ushort u) {
    return __uint_as_float(((uint32_t)u) << 16);
}

__device__ inline ushort f2bf_rne(float f) {
    uint32_t bits = __float_as_uint(f);
    uint32_t lsb = (bits >> 16) & 1u;
    bits += 0x7fffu + lsb;                 // round-to-nearest-even
    return (ushort)(bits >> 16);
}

// ---------------- MFMA GEMM body: H = A @ W, scaled bf16, 32-feat-pair out ---
// F32A=1: A read directly from fp32 x, converted to bf16 in registers (layer 1)
// F32A=0: A read as bf16 (layer 2). Hb[fp][v][32]. [m89/m91 verified mapping]
template<int F32A>
__device__ inline void gemm_body(const ushort* __restrict__ Xb,
                                 const float* __restrict__ Xf,
                                 const ushort* __restrict__ Wt,
                                 const float* __restrict__ dis,
                                 ushort* __restrict__ Hb, int gb, int tid) {
    int w = tid >> 6, lane = tid & 63;
    int m0 = gb * 128 + w * 32;
    int lrow = lane & 15, quad = lane >> 4;
    f32x4 acc[2][8] = {};
    for (int kt = 0; kt < DIM; kt += 32) {
        bfrag a[2], b[8];
        #pragma unroll
        for (int t = 0; t < 2; ++t) {
            int m = m0 + t * 16 + lrow;
            if (m >= N_NODES) m = 0;
            if (F32A) {
                const float* p = Xf + (size_t)m * DIM + kt + quad * 8;
                f32x4 v0 = *(const f32x4*)p;
                f32x4 v1 = *(const f32x4*)(p + 4);
                #pragma unroll
                for (int j = 0; j < 4; ++j) {
                    a[t][j]     = (short)f2bf_rne(v0[j]);
                    a[t][j + 4] = (short)f2bf_rne(v1[j]);
                }
            } else {
                a[t] = *(const bfrag*)(Xb + (size_t)m * DIM + kt + quad * 8);
            }
        }
        #pragma unroll
        for (int c = 0; c < 8; ++c) {
            int n = c * 16 + lrow;
            b[c] = *(const bfrag*)(Wt + (size_t)n * DIM + kt + quad * 8);
        }
        #pragma unroll
        for (int t = 0; t < 2; ++t)
            #pragma unroll
            for (int c = 0; c < 8; ++c)
                acc[t][c] = __builtin_amdgcn_mfma_f32_16x16x32_bf16(a[t], b[c], acc[t][c], 0, 0, 0);
    }
    #pragma unroll
    for (int t = 0; t < 2; ++t) {
        #pragma unroll
        for (int r = 0; r < 4; ++r) {
            int rowi = m0 + t * 16 + quad * 4 + r;
            if (rowi < N_NODES) {
                float dv = dis[rowi];
                #pragma unroll
                for (int c = 0; c < 8; ++c) {
                    int feat = c * 16 + lrow;
                    int fp = feat >> 5, off = feat & 31;
                    Hb[((size_t)fp * N_NODES + rowi) * 32 + off] = f2bf_rne(acc[t][c][r] * dv);
                }
            }
        }
    }
}

// ---- launch A: scatter FIRST (R18), then W transpose. x-convert is gone:
// layer-1 GEMM reads fp32 x directly and converts in-register.
__global__ __launch_bounds__(256) void k_prep(const float* __restrict__ W1,
                                              const float* __restrict__ W2,
                                              ushort* __restrict__ W1t,
                                              ushort* __restrict__ W2t,
                                              const int* __restrict__ src,
                                              const int* __restrict__ dst,
                                              uint32_t* __restrict__ gcur,
                                              uint32_t* __restrict__ packed) {
    __shared__ uint32_t h[NB];
    int b = blockIdx.x;
    int t = threadIdx.x;
    if (b < NBLK) {
        uint32_t dc[CHUNK / 256], sc[CHUNK / 256];   // static-indexed reg cache
        if (t < NB) h[t] = 0u;
        __syncthreads();
        int base = b * CHUNK;
        #pragma unroll
        for (int i = 0; i < CHUNK / 256; ++i) {
            int e = base + i * 256 + t;
            if (e < N_EDGES) {
                dc[i] = (uint32_t)dst[e];
                sc[i] = (uint32_t)src[e];
                atomicAdd(&h[dc[i] >> 8], 1u);
            } else {
                dc[i] = 0xffffffffu;
            }
        }
        __syncthreads();
        if (t < NB) {
            uint32_t c = h[t];
            h[t] = c ? atomicAdd(&gcur[t], c) : 0u;   // reserve contiguous run
        }
        __syncthreads();
        #pragma unroll
        for (int i = 0; i < CHUNK / 256; ++i) {
            if (dc[i] != 0xffffffffu) {
                uint32_t d = dc[i];
                uint32_t s = sc[i];
                uint32_t bk = d >> 8;
                uint32_t pos = atomicAdd(&h[bk], 1u);
                if (pos < CAP)
                    packed[(size_t)bk * CAP + pos] = ((d & 255u) << 16) | s;
            }
        }
    } else {
        int j = (b - NBLK) * 256 + t;              // 0..32767
        const float* W = (j < DIM * DIM) ? W1 : W2;
        ushort* Wt = (j < DIM * DIM) ? W1t : W2t;
        int i = j & (DIM * DIM - 1);
        int k = i >> 7, n = i & 127;
        Wt[n * DIM + k] = f2bf_rne(W[k * DIM + n]);
    }
}

// ---- k_fill: per-bucket CSR -> COMPACT space; also writes row & dis ---------
// Compact base = LDS scan of gcur[0..b) (R16 fix). mine[] reg-cache replaced by
// an L1/L2-hot re-read of packed[] (runtime-indexed array -> scratch, rule #20).
__global__ __launch_bounds__(256) void k_fill(const uint32_t* __restrict__ gcur,
                                              const uint32_t* __restrict__ packed,
                                              uint32_t* __restrict__ row,
                                              float* __restrict__ dis,
                                              ushort* __restrict__ col16) {
    __shared__ uint32_t sdeg[256];
    __shared__ uint32_t scan[256];
    __shared__ uint32_t cur[256];
    int b = blockIdx.x;
    int t = threadIdx.x;
    uint32_t n = gcur[b];
    scan[t] = (t < b) ? gcur[t] : 0u;              // b <= 195 < 256
    __syncthreads();
    for (int off = 1; off < 256; off <<= 1) {
        uint32_t x = (t >= off) ? scan[t - off] : 0u;
        __syncthreads();
        scan[t] += x;
        __syncthreads();
    }
    uint32_t cbase = scan[255];
    __syncthreads();
    uint32_t pbase = (uint32_t)b * CAP;
    sdeg[t] = 0u;
    __syncthreads();
    for (uint32_t i = t; i < n; i += 256) {
        uint32_t u = packed[pbase + i];
        atomicAdd(&sdeg[u >> 16], 1u);
    }
    __syncthreads();
    uint32_t myd = sdeg[t];
    scan[t] = myd;
    __syncthreads();
    for (int off = 1; off < 256; off <<= 1) {
        uint32_t x = (t >= off) ? scan[t - off] : 0u;
        __syncthreads();
        scan[t] += x;
        __syncthreads();
    }
    uint32_t excl = scan[t] - myd;
    cur[t] = excl;
    int v = b * 256 + t;
    if (v <= N_NODES) row[v] = cbase + excl;       // compact; row[50000]=800000
    if (v < N_NODES)  dis[v] = 1.0f / sqrtf((float)(myd + 1u));
    __syncthreads();
    for (uint32_t i = t; i < n; i += 256) {        // re-read: L1-hot, no scratch
        uint32_t u = packed[pbase + i];
        uint32_t pos = cbase + atomicAdd(&cur[u >> 16], 1u);
        col16[pos] = (ushort)(u & 0xffffu);
    }
}

// ---------------- fused gather + bias + leaky + dropout [+ classifier] -------
// Block (fp = blockIdx&3 -> 32-feat pair, c): 64 nodes; thread=(node, 8-feat q).
// CLS=0: store bf16 activations to OUTb (layer 1).
// CLS=1: fold the 128->2 classifier GEMM into the epilogue (layer 2): z stays
//        in registers, dot with W3, 4-lane shfl reduce, 1 fp32 atomic pair per
//        node-quarter-group. Bb round-trip (25.6 MB) + k_gemm_cls eliminated.
template<int CLS>
__global__ __launch_bounds__(256) void k_gather_t(const uint32_t* __restrict__ row,
                                                  const ushort* __restrict__ col16,
                                                  const float* __restrict__ dis,
                                                  const ushort* __restrict__ Hb,
                                                  const float* __restrict__ bias,
                                                  ushort* __restrict__ OUTb,
                                                  const float* __restrict__ W3,
                                                  float* __restrict__ h3s,
                                                  uint32_t kk0, uint32_t kk1) {
    __shared__ ushort scol[GCAP];
    __shared__ uint32_t srow[65];
    int fp = blockIdx.x & 3;
    int c = blockIdx.x >> 2;
    int tid = threadIdx.x;
    int nbase = c * 64;
    int nend = nbase + 64; if (nend > N_NODES) nend = N_NODES;
    int nloc = nend - nbase;
    for (int i = tid; i <= nloc; i += 256) srow[i] = row[nbase + i];
    __syncthreads();
    uint32_t eLo = srow[0];
    uint32_t count = srow[nloc] - eLo;
    bool staged = count <= GCAP;
    if (staged) {
        for (uint32_t i = tid; i < count; i += 256) scol[i] = col16[eLo + i];
    }
    __syncthreads();

    int nl = tid >> 2;                 // node in block
    int q  = tid & 3;                  // 8-feat quarter of the 32-feat pair
    int v = nbase + nl;
    if (v >= N_NODES) return;
    const ushort* Hf = Hb + (size_t)fp * N_NODES * 32;
    ushort8_t hv = *((const ushort8_t*)(Hf + (size_t)v * 32 + q * 8));
    float acc[8];
    #pragma unroll
    for (int j = 0; j < 8; ++j) acc[j] = bf2f(hv[j]);

    uint32_t e0 = srow[nl] - eLo, e1 = srow[nl + 1] - eLo;
    uint32_t e = e0;
    if (staged) {
        for (; e + 4 <= e1; e += 4) {
            uint32_t s0 = scol[e], s1 = scol[e + 1], s2 = scol[e + 2], s3 = scol[e + 3];
            ushort8_t h0 = *((const ushort8_t*)(Hf + (size_t)s0 * 32 + q * 8));
            ushort8_t h1 = *((const ushort8_t*)(Hf + (size_t)s1 * 32 + q * 8));
            ushort8_t h2 = *((const ushort8_t*)(Hf + (size_t)s2 * 32 + q * 8));
            ushort8_t h3 = *((const ushort8_t*)(Hf + (size_t)s3 * 32 + q * 8));
            #pragma unroll
            for (int j = 0; j < 8; ++j)
                acc[j] += (bf2f(h0[j]) + bf2f(h1[j])) + (bf2f(h2[j]) + bf2f(h3[j]));
        }
        for (; e < e1; ++e) {
            uint32_t s0 = scol[e];
            ushort8_t h0 = *((const ushort8_t*)(Hf + (size_t)s0 * 32 + q * 8));
            #pragma unroll
            for (int j = 0; j < 8; ++j) acc[j] += bf2f(h0[j]);
        }
    } else {
        for (; e < e1; ++e) {
            uint32_t s0 = col16[eLo + e];
            ushort8_t h0 = *((const ushort8_t*)(Hf + (size_t)s0 * 32 + q * 8));
            #pragma unroll
            for (int j = 0; j < 8; ++j) acc[j] += bf2f(h0[j]);
        }
    }

    float dv = dis[v];
    int cbase = fp * 32 + q * 8;
    uint32_t ibase = (uint32_t)(v * DIM + cbase);
    if (CLS == 0) {
        ushort8_t o;
        #pragma unroll
        for (int j = 0; j < 8; ++j) {
            float z = acc[j] * dv + bias[cbase + j];
            z = (z >= 0.f) ? z : 0.01f * z;
            z *= drop_scale(kk0, kk1, ibase + j);
            o[j] = f2bf_rne(z);
        }
        *((ushort8_t*)(OUTb + (size_t)v * DIM + cbase)) = o;
    } else {
        float o0 = 0.f, o1 = 0.f;
        #pragma unroll
        for (int j = 0; j < 8; ++j) {
            float z = acc[j] * dv + bias[cbase + j];
            z = (z >= 0.f) ? z : 0.01f * z;
            z *= drop_scale(kk0, kk1, ibase + j);
            o0 += z * W3[(cbase + j) * 2 + 0];
            o1 += z * W3[(cbase + j) * 2 + 1];
        }
        // reduce the 4 q-lanes (consecutive lanes, same node)
        o0 += __shfl_xor(o0, 1); o0 += __shfl_xor(o0, 2);
        o1 += __shfl_xor(o1, 1); o1 += __shfl_xor(o1, 2);
        if (q == 0) {
            atomicAdd(&h3s[v * 2 + 0], o0 * dv);   // src-side dis for layer 3
            atomicAdd(&h3s[v * 2 + 1], o1 * dv);
        }
    }
}

// ---------------- MFMA GEMM launchers ----------------
__global__ __launch_bounds__(256) void k_gemm_f32(const float* __restrict__ Xf,
                                                  const ushort* __restrict__ Wt,
                                                  const float* __restrict__ dis,
                                                  ushort* __restrict__ Hb) {
    gemm_body<1>(nullptr, Xf, Wt, dis, Hb, blockIdx.x, threadIdx.x);
}
__global__ __launch_bounds__(256) void k_gemm_bf16(const ushort* __restrict__ Xb,
                                                   const ushort* __restrict__ Wt,
                                                   const float* __restrict__ dis,
                                                   ushort* __restrict__ Hb) {
    gemm_body<0>(Xb, nullptr, Wt, dis, Hb, blockIdx.x, threadIdx.x);
}

// ---------------- fused layer-3 gather + bias + log_softmax, LDS-staged ------
__global__ __launch_bounds__(256) void k_gather3(const uint32_t* __restrict__ row,
                                                 const ushort* __restrict__ col16,
                                                 const float* __restrict__ dis,
                                                 const float* __restrict__ H3s,
                                                 const float* __restrict__ b3,
                                                 float* __restrict__ out) {
    __shared__ ushort scol[G3CAP];
    __shared__ uint32_t srow[257];
    int tid = threadIdx.x;
    int nbase = blockIdx.x * 256;
    int nend = nbase + 256; if (nend > N_NODES) nend = N_NODES;
    int nloc = nend - nbase;
    for (int i = tid; i <= nloc; i += 256) srow[i] = row[nbase + i];
    __syncthreads();
    uint32_t eLo = srow[0];
    uint32_t count = srow[nloc] - eLo;
    bool staged = count <= G3CAP;
    if (staged) {
        for (uint32_t i = tid; i < count; i += 256) scol[i] = col16[eLo + i];
    }
    __syncthreads();

    int v = nbase + tid;
    if (v >= N_NODES) return;
    const float2* H2 = (const float2*)H3s;
    float2 h = H2[v];
    float z0 = h.x, z1 = h.y;
    uint32_t e0 = srow[tid] - eLo, e1 = srow[tid + 1] - eLo;
    uint32_t e = e0;
    if (staged) {
        for (; e + 2 <= e1; e += 2) {
            float2 ha = H2[scol[e]];
            float2 hb = H2[scol[e + 1]];
            z0 += ha.x + hb.x; z1 += ha.y + hb.y;
        }
        if (e < e1) {
            float2 ha = H2[scol[e]];
            z0 += ha.x; z1 += ha.y;
        }
    } else {
        for (; e < e1; ++e) {
            float2 ha = H2[col16[eLo + e]];
            z0 += ha.x; z1 += ha.y;
        }
    }
    float dv = dis[v];
    z0 = z0 * dv + b3[0];
    z1 = z1 * dv + b3[1];
    float m = fmaxf(z0, z1);
    float lse = m + logf(expf(z0 - m) + expf(z1 - m));
    out[v * 2 + 0] = z0 - lse;
    out[v * 2 + 1] = z1 - lse;
}

extern "C" void kernel_launch(void* const* d_in, const int* in_sizes, int n_in,
                              void* d_out, int out_size, void* d_ws, size_t ws_size,
                              hipStream_t stream) {
    const float* x  = (const float*)d_in[0];
    const int*   ei = (const int*)d_in[1];
    const float* W1 = (const float*)d_in[2];
    const float* b1 = (const float*)d_in[3];
    const float* W2 = (const float*)d_in[4];
    const float* b2 = (const float*)d_in[5];
    const float* W3 = (const float*)d_in[6];
    const float* b3 = (const float*)d_in[7];
    float* out = (float*)d_out;

    const int* src = ei;
    const int* dst = ei + N_EDGES;

    // workspace layout (u32 units) -- all regions disjoint (R10 lesson)
    uint32_t* wsu = (uint32_t*)d_ws;
    float*    wsf = (float*)d_ws;
    uint32_t* gcur   = wsu;                       // [0, 196) -> pad 256
    uint32_t* row    = wsu + 256;                 // [256, 50257) -> pad 50304
    float*    dis    = wsf + 50304;               // [50304, 100304) -> pad 100352
    uint32_t* packed = wsu + 100352;              // 196*8192 -> [100352, 1705984)
    ushort*   col16  = (ushort*)(wsu + 1705984);  // 800000 u16 -> pad to 2106112
    ushort*   Hb     = (ushort*)(wsu + 2106112);  // [2106112, 5306112)
    ushort*   Bb     = (ushort*)(wsu + 8506112);  // [8506112, 11706112)
    ushort*   W1t    = (ushort*)(wsu + 11706112); // [11706112, 11714304)
    ushort*   W2t    = (ushort*)(wsu + 11714304); // [11714304, 11722496)
    float*    h3s    = wsf + 11722496;            // [11722496, 11822496)

    // dropout keys: threefry-partitionable fold-like split of key(42) (verified R0)
    uint32_t k1a, k1b, k2a, k2b;
    threefry2x32(0u, 42u, 0u, 0u, k1a, k1b);
    threefry2x32(0u, 42u, 0u, 1u, k2a, k2b);

    hipMemsetAsync(gcur, 0, 256 * sizeof(uint32_t), stream);
    hipMemsetAsync(h3s, 0, N_NODES * 2 * sizeof(float), stream);  // cls atomics

    // ---- A: scatter (first!) | W transpose (x-convert folded into GEMM-1) ----
    k_prep<<<NBLK + 128, 256, 0, stream>>>(W1, W2, W1t, W2t,
                                           src, dst, gcur, packed);

    // ---- CSR fill (compact; writes row/dis/col16) ----
    k_fill<<<NB, 256, 0, stream>>>(gcur, packed, row, dis, col16);

    int mgrid = (N_NODES + 127) / 128;                   // 391
    int ggrid = ((N_NODES + 63) / 64) * 4;               // (fp, 64-node chunk)

    // ---- layer 1: GEMM reads fp32 x directly ----
    k_gemm_f32<<<mgrid, 256, 0, stream>>>(x, W1t, dis, Hb);
    k_gather_t<0><<<ggrid, 256, 0, stream>>>(row, col16, dis, Hb, b1, Bb,
                                             nullptr, nullptr, k1a, k1b);

    // ---- layer 2 + fused 128->2 classifier ----
    k_gemm_bf16<<<mgrid, 256, 0, stream>>>(Bb, W2t, dis, Hb);
    k_gather_t<1><<<ggrid, 256, 0, stream>>>(row, col16, dis, Hb, b2, nullptr,
                                             W3, h3s, k2a, k2b);

    // ---- layer 3 aggregate + log_softmax ----
    k_gather3<<<(N_NODES + 255) / 256, 256, 0, stream>>>(row, col16, dis, h3s, b3, out);
}

// Round 2
// 215.287 us; speedup vs baseline: 1.0770x; 1.0385x over previous
//
#include <hip/hip_runtime.h>
#include <stdint.h>

#define N_NODES 50000
#define N_EDGES 800000
#define DIM     128
#define NB   196                 // dst buckets: dst>>8
#define CAP  8192                // fixed slots per bucket in 'packed'
#define CHUNK 2048               // edges per scatter block
#define NBLK 391                 // ceil(800000/2048)
#define GNODES 16                // nodes per gather block (50000 = 16*3125)
#define GGRID 3125
#define GCAP2 2048               // LDS edge cap per gather block (mean 256)
#define G3CAP 8192               // LDS edge cap for gather3 blocks
#define ZBLK 98                  // h3s zero blocks: 25000 f32x4 / 256

typedef __attribute__((ext_vector_type(8))) unsigned short ushort8_t;
typedef __attribute__((ext_vector_type(8))) short bfrag;    // 8 bf16 = 4 VGPR
typedef __attribute__((ext_vector_type(4))) float f32x4;

// ---------------- Threefry-2x32 (exact JAX 20-round) ----------------
__host__ __device__ inline void threefry2x32(uint32_t k0, uint32_t k1,
                                             uint32_t x0, uint32_t x1,
                                             uint32_t& o0, uint32_t& o1) {
    uint32_t ks0 = k0, ks1 = k1, ks2 = k0 ^ k1 ^ 0x1BD11BDAu;
    uint32_t v0 = x0 + ks0, v1 = x1 + ks1;
#define TF_R(r) { v0 += v1; v1 = (v1 << (r)) | (v1 >> (32 - (r))); v1 ^= v0; }
    TF_R(13) TF_R(15) TF_R(26) TF_R(6)
    v0 += ks1; v1 += ks2 + 1u;
    TF_R(17) TF_R(29) TF_R(16) TF_R(24)
    v0 += ks2; v1 += ks0 + 2u;
    TF_R(13) TF_R(15) TF_R(26) TF_R(6)
    v0 += ks0; v1 += ks1 + 3u;
    TF_R(17) TF_R(29) TF_R(16) TF_R(24)
    v0 += ks1; v1 += ks2 + 4u;
    TF_R(13) TF_R(15) TF_R(26) TF_R(6)
    v0 += ks2; v1 += ks0 + 5u;
#undef TF_R
    o0 = v0; o1 = v1;
}

__device__ inline float drop_scale(uint32_t kk0, uint32_t kk1, uint32_t i) {
    uint32_t b0, b1;
    threefry2x32(kk0, kk1, 0u, i, b0, b1);
    uint32_t bits = b0 ^ b1;               // partitionable 32-bit path (verified R0)
    return (bits >> 31) ? 0.0f : 2.0f;     // keep iff u < 0.5 iff top bit 0
}

__device__ inline float bf2f(ushort u) {
    return __uint_as_float(((uint32_t)u) << 16);
}

__device__ inline ushort f2bf_rne(float f) {
    uint32_t bits = __float_as_uint(f);
    uint32_t lsb = (bits >> 16) & 1u;
    bits += 0x7fffu + lsb;                 // round-to-nearest-even
    return (ushort)(bits >> 16);
}

// ---------------- MFMA GEMM body: H = A @ W, bf16 out, Hb[v][128] -----------
// F32A=1: A read from fp32, converted in registers (layer 1)
// F32A=0: A read as bf16 (layer 2)
// SCALE=1: pre-multiply rows by dis[row] (layer 2); SCALE=0: raw (layer 1 —
//          dis not yet available when gemm runs inside k_fill; gather applies it)
template<int F32A, int SCALE>
__device__ inline void gemm_body(const ushort* __restrict__ Xb,
                                 const float* __restrict__ Xf,
                                 const ushort* __restrict__ Wt,
                                 const float* __restrict__ dis,
                                 ushort* __restrict__ Hb, int gb, int tid) {
    int w = tid >> 6, lane = tid & 63;
    int m0 = gb * 128 + w * 32;
    int lrow = lane & 15, quad = lane >> 4;
    f32x4 acc[2][8] = {};
    for (int kt = 0; kt < DIM; kt += 32) {
        bfrag a[2], b[8];
        #pragma unroll
        for (int t = 0; t < 2; ++t) {
            int m = m0 + t * 16 + lrow;
            if (m >= N_NODES) m = 0;
            if (F32A) {
                const float* p = Xf + (size_t)m * DIM + kt + quad * 8;
                f32x4 v0 = *(const f32x4*)p;
                f32x4 v1 = *(const f32x4*)(p + 4);
                #pragma unroll
                for (int j = 0; j < 4; ++j) {
                    a[t][j]     = (short)f2bf_rne(v0[j]);
                    a[t][j + 4] = (short)f2bf_rne(v1[j]);
                }
            } else {
                a[t] = *(const bfrag*)(Xb + (size_t)m * DIM + kt + quad * 8);
            }
        }
        #pragma unroll
        for (int c = 0; c < 8; ++c) {
            int n = c * 16 + lrow;
            b[c] = *(const bfrag*)(Wt + (size_t)n * DIM + kt + quad * 8);
        }
        #pragma unroll
        for (int t = 0; t < 2; ++t)
            #pragma unroll
            for (int c = 0; c < 8; ++c)
                acc[t][c] = __builtin_amdgcn_mfma_f32_16x16x32_bf16(a[t], b[c], acc[t][c], 0, 0, 0);
    }
    #pragma unroll
    for (int t = 0; t < 2; ++t) {
        #pragma unroll
        for (int r = 0; r < 4; ++r) {
            int rowi = m0 + t * 16 + quad * 4 + r;
            if (rowi < N_NODES) {
                float dv = SCALE ? dis[rowi] : 1.0f;
                #pragma unroll
                for (int c = 0; c < 8; ++c) {
                    int feat = c * 16 + lrow;
                    float z = SCALE ? acc[t][c][r] * dv : acc[t][c][r];
                    Hb[(size_t)rowi * DIM + feat] = f2bf_rne(z);
                }
            }
        }
    }
}

// ---- k_prep: scatter FIRST (R18: latency-bound blocks at t=0), then W
// transposes, then h3s zeroing (folds away a memset dispatch).
__global__ __launch_bounds__(256) void k_prep(const float* __restrict__ W1,
                                              const float* __restrict__ W2,
                                              ushort* __restrict__ W1t,
                                              ushort* __restrict__ W2t,
                                              const int* __restrict__ src,
                                              const int* __restrict__ dst,
                                              uint32_t* __restrict__ gcur,
                                              uint32_t* __restrict__ packed,
                                              float* __restrict__ h3s) {
    __shared__ uint32_t h[NB];
    int b = blockIdx.x;
    int t = threadIdx.x;
    if (b < NBLK) {
        uint32_t dc[CHUNK / 256], sc[CHUNK / 256];   // static-indexed reg cache
        if (t < NB) h[t] = 0u;
        __syncthreads();
        int base = b * CHUNK;
        #pragma unroll
        for (int i = 0; i < CHUNK / 256; ++i) {
            int e = base + i * 256 + t;
            if (e < N_EDGES) {
                dc[i] = (uint32_t)dst[e];
                sc[i] = (uint32_t)src[e];
                atomicAdd(&h[dc[i] >> 8], 1u);
            } else {
                dc[i] = 0xffffffffu;
            }
        }
        __syncthreads();
        if (t < NB) {
            uint32_t c = h[t];
            h[t] = c ? atomicAdd(&gcur[t], c) : 0u;   // reserve contiguous run
        }
        __syncthreads();
        #pragma unroll
        for (int i = 0; i < CHUNK / 256; ++i) {
            if (dc[i] != 0xffffffffu) {
                uint32_t d = dc[i];
                uint32_t s = sc[i];
                uint32_t bk = d >> 8;
                uint32_t pos = atomicAdd(&h[bk], 1u);
                if (pos < CAP)
                    packed[(size_t)bk * CAP + pos] = ((d & 255u) << 16) | s;
            }
        }
    } else if (b < NBLK + 128) {
        int j = (b - NBLK) * 256 + t;              // 0..32767
        const float* W = (j < DIM * DIM) ? W1 : W2;
        ushort* Wt = (j < DIM * DIM) ? W1t : W2t;
        int i = j & (DIM * DIM - 1);
        int k = i >> 7, n = i & 127;
        Wt[n * DIM + k] = f2bf_rne(W[k * DIM + n]);
    } else {
        int idx = (b - NBLK - 128) * 256 + t;      // zero h3s (25000 f32x4)
        if (idx < (N_NODES * 2) / 4) {
            f32x4 z = {0.f, 0.f, 0.f, 0.f};
            ((f32x4*)h3s)[idx] = z;
        }
    }
}

// ---- k_fill: csr blocks (0..195, latency-bound, start at t=0) build the
// compact CSR + dis; gemm blocks (196..586) run layer-1 GEMM concurrently
// (reads only x/W1t — no dependence on csr output; writes UNSCALED Hb).
__global__ __launch_bounds__(256) void k_fill(const uint32_t* __restrict__ gcur,
                                              const uint32_t* __restrict__ packed,
                                              uint32_t* __restrict__ row,
                                              float* __restrict__ dis,
                                              ushort* __restrict__ col16,
                                              const float* __restrict__ x,
                                              const ushort* __restrict__ W1t,
                                              ushort* __restrict__ Hb) {
    __shared__ uint32_t sdeg[256];
    __shared__ uint32_t scan[256];
    __shared__ uint32_t cur[256];
    int b = blockIdx.x;
    int t = threadIdx.x;
    if (b >= NB) {                                  // layer-1 GEMM flavor
        gemm_body<1, 0>(nullptr, x, W1t, nullptr, Hb, b - NB, t);
        return;
    }
    uint32_t n = gcur[b];
    scan[t] = (t < b) ? gcur[t] : 0u;              // b <= 195 < 256
    __syncthreads();
    for (int off = 1; off < 256; off <<= 1) {
        uint32_t xx = (t >= off) ? scan[t - off] : 0u;
        __syncthreads();
        scan[t] += xx;
        __syncthreads();
    }
    uint32_t cbase = scan[255];
    __syncthreads();
    uint32_t pbase = (uint32_t)b * CAP;
    sdeg[t] = 0u;
    __syncthreads();
    for (uint32_t i = t; i < n; i += 256) {
        uint32_t u = packed[pbase + i];
        atomicAdd(&sdeg[u >> 16], 1u);
    }
    __syncthreads();
    uint32_t myd = sdeg[t];
    scan[t] = myd;
    __syncthreads();
    for (int off = 1; off < 256; off <<= 1) {
        uint32_t xx = (t >= off) ? scan[t - off] : 0u;
        __syncthreads();
        scan[t] += xx;
        __syncthreads();
    }
    uint32_t excl = scan[t] - myd;
    cur[t] = excl;
    int v = b * 256 + t;
    if (v <= N_NODES) row[v] = cbase + excl;       // compact; row[50000]=800000
    if (v < N_NODES)  dis[v] = 1.0f / sqrtf((float)(myd + 1u));
    __syncthreads();
    for (uint32_t i = t; i < n; i += 256) {        // re-read: L1-hot, no scratch
        uint32_t u = packed[pbase + i];
        uint32_t pos = cbase + atomicAdd(&cur[u >> 16], 1u);
        col16[pos] = (ushort)(u & 0xffffu);
    }
}

// ---------------- fused gather + bias + leaky + dropout [+ classifier] -------
// Block: 16 nodes, ALL 128 feats. thread = (node nl = tid>>4, 8-feat q = tid&15).
// Wave = 4 nodes (max-of-4 degree ~20 vs max-of-16 ~23: less divergence waste);
// per edge a 16-lane group reads one contiguous 256B line of Hb[v][128].
// SRCDIS=1 (layer 1): Hb unscaled -> apply dis[s] per edge, dis[v] on self/out.
// CLS=1 (layer 2): fold 128->2 classifier; 16-lane shfl reduce, atomics to h3s.
template<int CLS, int SRCDIS>
__global__ __launch_bounds__(256) void k_gather_t(const uint32_t* __restrict__ row,
                                                  const ushort* __restrict__ col16,
                                                  const float* __restrict__ dis,
                                                  const ushort* __restrict__ Hb,
                                                  const float* __restrict__ bias,
                                                  ushort* __restrict__ OUTb,
                                                  const float* __restrict__ W3,
                                                  float* __restrict__ h3s,
                                                  uint32_t kk0, uint32_t kk1) {
    __shared__ ushort scol[GCAP2];
    __shared__ uint32_t srow[GNODES + 1];
    int tid = threadIdx.x;
    int nbase = blockIdx.x * GNODES;
    if (tid <= GNODES) srow[tid] = row[nbase + tid];
    __syncthreads();
    uint32_t eLo = srow[0];
    uint32_t count = srow[GNODES] - eLo;
    bool staged = count <= GCAP2;
    if (staged) {
        for (uint32_t i = tid; i < count; i += 256) scol[i] = col16[eLo + i];
    }
    __syncthreads();

    int nl = tid >> 4;                 // node in block (0..15)
    int q  = tid & 15;                 // 8-feat slice (0..15)
    int v = nbase + nl;                // always < N_NODES (50000 = 16*3125)
    float dv = dis[v];
    ushort8_t hv = *((const ushort8_t*)(Hb + (size_t)v * DIM + q * 8));
    float acc[8];
    #pragma unroll
    for (int j = 0; j < 8; ++j)
        acc[j] = SRCDIS ? dv * bf2f(hv[j]) : bf2f(hv[j]);   // self-loop term

    uint32_t e0 = srow[nl] - eLo, e1 = srow[nl + 1] - eLo;
    uint32_t e = e0;
    if (staged) {
        for (; e + 4 <= e1; e += 4) {
            uint32_t s0 = scol[e], s1 = scol[e + 1], s2 = scol[e + 2], s3 = scol[e + 3];
            ushort8_t h0 = *((const ushort8_t*)(Hb + (size_t)s0 * DIM + q * 8));
            ushort8_t h1 = *((const ushort8_t*)(Hb + (size_t)s1 * DIM + q * 8));
            ushort8_t h2 = *((const ushort8_t*)(Hb + (size_t)s2 * DIM + q * 8));
            ushort8_t h3 = *((const ushort8_t*)(Hb + (size_t)s3 * DIM + q * 8));
            if (SRCDIS) {
                float d0 = dis[s0], d1 = dis[s1], d2 = dis[s2], d3 = dis[s3];
                #pragma unroll
                for (int j = 0; j < 8; ++j)
                    acc[j] += d0 * bf2f(h0[j]) + d1 * bf2f(h1[j])
                            + d2 * bf2f(h2[j]) + d3 * bf2f(h3[j]);
            } else {
                #pragma unroll
                for (int j = 0; j < 8; ++j)
                    acc[j] += (bf2f(h0[j]) + bf2f(h1[j])) + (bf2f(h2[j]) + bf2f(h3[j]));
            }
        }
        for (; e < e1; ++e) {
            uint32_t s0 = scol[e];
            ushort8_t h0 = *((const ushort8_t*)(Hb + (size_t)s0 * DIM + q * 8));
            float d0 = SRCDIS ? dis[s0] : 1.0f;
            #pragma unroll
            for (int j = 0; j < 8; ++j)
                acc[j] += SRCDIS ? d0 * bf2f(h0[j]) : bf2f(h0[j]);
        }
    } else {
        for (; e < e1; ++e) {
            uint32_t s0 = col16[eLo + e];
            ushort8_t h0 = *((const ushort8_t*)(Hb + (size_t)s0 * DIM + q * 8));
            float d0 = SRCDIS ? dis[s0] : 1.0f;
            #pragma unroll
            for (int j = 0; j < 8; ++j)
                acc[j] += SRCDIS ? d0 * bf2f(h0[j]) : bf2f(h0[j]);
        }
    }

    int cbase = q * 8;
    uint32_t ibase = (uint32_t)(v * DIM + cbase);
    if (CLS == 0) {
        ushort8_t o;
        #pragma unroll
        for (int j = 0; j < 8; ++j) {
            float z = acc[j] * dv + bias[cbase + j];
            z = (z >= 0.f) ? z : 0.01f * z;
            z *= drop_scale(kk0, kk1, ibase + j);
            o[j] = f2bf_rne(z);
        }
        *((ushort8_t*)(OUTb + (size_t)v * DIM + cbase)) = o;
    } else {
        float o0 = 0.f, o1 = 0.f;
        #pragma unroll
        for (int j = 0; j < 8; ++j) {
            float z = acc[j] * dv + bias[cbase + j];
            z = (z >= 0.f) ? z : 0.01f * z;
            z *= drop_scale(kk0, kk1, ibase + j);
            o0 += z * W3[(cbase + j) * 2 + 0];
            o1 += z * W3[(cbase + j) * 2 + 1];
        }
        // reduce the 16 q-lanes (consecutive lanes, same node)
        o0 += __shfl_xor(o0, 1); o0 += __shfl_xor(o0, 2);
        o0 += __shfl_xor(o0, 4); o0 += __shfl_xor(o0, 8);
        o1 += __shfl_xor(o1, 1); o1 += __shfl_xor(o1, 2);
        o1 += __shfl_xor(o1, 4); o1 += __shfl_xor(o1, 8);
        if (q == 0) {
            atomicAdd(&h3s[v * 2 + 0], o0 * dv);   // src-side dis for layer 3
            atomicAdd(&h3s[v * 2 + 1], o1 * dv);
        }
    }
}

// ---------------- layer-2 MFMA GEMM launcher (dis-prescaled output) ----------
__global__ __launch_bounds__(256) void k_gemm_bf16(const ushort* __restrict__ Xb,
                                                   const ushort* __restrict__ Wt,
                                                   const float* __restrict__ dis,
                                                   ushort* __restrict__ Hb) {
    gemm_body<0, 1>(Xb, nullptr, Wt, dis, Hb, blockIdx.x, threadIdx.x);
}

// ---------------- fused layer-3 gather + bias + log_softmax, LDS-staged ------
__global__ __launch_bounds__(256) void k_gather3(const uint32_t* __restrict__ row,
                                                 const ushort* __restrict__ col16,
                                                 const float* __restrict__ dis,
                                                 const float* __restrict__ H3s,
                                                 const float* __restrict__ b3,
                                                 float* __restrict__ out) {
    __shared__ ushort scol[G3CAP];
    __shared__ uint32_t srow[257];
    int tid = threadIdx.x;
    int nbase = blockIdx.x * 256;
    int nend = nbase + 256; if (nend > N_NODES) nend = N_NODES;
    int nloc = nend - nbase;
    for (int i = tid; i <= nloc; i += 256) srow[i] = row[nbase + i];
    __syncthreads();
    uint32_t eLo = srow[0];
    uint32_t count = srow[nloc] - eLo;
    bool staged = count <= G3CAP;
    if (staged) {
        for (uint32_t i = tid; i < count; i += 256) scol[i] = col16[eLo + i];
    }
    __syncthreads();

    int v = nbase + tid;
    if (v >= N_NODES) return;
    const float2* H2 = (const float2*)H3s;
    float2 h = H2[v];
    float z0 = h.x, z1 = h.y;
    uint32_t e0 = srow[tid] - eLo, e1 = srow[tid + 1] - eLo;
    uint32_t e = e0;
    if (staged) {
        for (; e + 2 <= e1; e += 2) {
            float2 ha = H2[scol[e]];
            float2 hb = H2[scol[e + 1]];
            z0 += ha.x + hb.x; z1 += ha.y + hb.y;
        }
        if (e < e1) {
            float2 ha = H2[scol[e]];
            z0 += ha.x; z1 += ha.y;
        }
    } else {
        for (; e < e1; ++e) {
            float2 ha = H2[col16[eLo + e]];
            z0 += ha.x; z1 += ha.y;
        }
    }
    float dv = dis[v];
    z0 = z0 * dv + b3[0];
    z1 = z1 * dv + b3[1];
    float m = fmaxf(z0, z1);
    float lse = m + logf(expf(z0 - m) + expf(z1 - m));
    out[v * 2 + 0] = z0 - lse;
    out[v * 2 + 1] = z1 - lse;
}

extern "C" void kernel_launch(void* const* d_in, const int* in_sizes, int n_in,
                              void* d_out, int out_size, void* d_ws, size_t ws_size,
                              hipStream_t stream) {
    const float* x  = (const float*)d_in[0];
    const int*   ei = (const int*)d_in[1];
    const float* W1 = (const float*)d_in[2];
    const float* b1 = (const float*)d_in[3];
    const float* W2 = (const float*)d_in[4];
    const float* b2 = (const float*)d_in[5];
    const float* W3 = (const float*)d_in[6];
    const float* b3 = (const float*)d_in[7];
    float* out = (float*)d_out;

    const int* src = ei;
    const int* dst = ei + N_EDGES;

    // workspace layout (u32 units) -- all regions disjoint (R10 lesson)
    uint32_t* wsu = (uint32_t*)d_ws;
    float*    wsf = (float*)d_ws;
    uint32_t* gcur   = wsu;                       // [0, 196) -> pad 256
    uint32_t* row    = wsu + 256;                 // [256, 50257) -> pad 50304
    float*    dis    = wsf + 50304;               // [50304, 100304) -> pad 100352
    uint32_t* packed = wsu + 100352;              // 196*8192 -> [100352, 1705984)
    ushort*   col16  = (ushort*)(wsu + 1705984);  // 800000 u16 -> pad to 2106112
    ushort*   Hb     = (ushort*)(wsu + 2106112);  // [2106112, 5306112)
    ushort*   Bb     = (ushort*)(wsu + 8506112);  // [8506112, 11706112)
    ushort*   W1t    = (ushort*)(wsu + 11706112); // [11706112, 11714304)
    ushort*   W2t    = (ushort*)(wsu + 11714304); // [11714304, 11722496)
    float*    h3s    = wsf + 11722496;            // [11722496, 11822496)

    // dropout keys: threefry-partitionable fold-like split of key(42) (verified R0)
    uint32_t k1a, k1b, k2a, k2b;
    threefry2x32(0u, 42u, 0u, 0u, k1a, k1b);
    threefry2x32(0u, 42u, 0u, 1u, k2a, k2b);

    hipMemsetAsync(gcur, 0, 256 * sizeof(uint32_t), stream);

    // ---- A: scatter (first!) | W transpose | h3s zero ----
    k_prep<<<NBLK + 128 + ZBLK, 256, 0, stream>>>(W1, W2, W1t, W2t,
                                                  src, dst, gcur, packed, h3s);

    // ---- CSR fill (csr blocks) OVERLAPPED with layer-1 GEMM (gemm blocks) ----
    k_fill<<<NB + 391, 256, 0, stream>>>(gcur, packed, row, dis, col16,
                                         x, W1t, Hb);

    // ---- layer 1 gather (applies dis[s] per edge since Hb is unscaled) ----
    k_gather_t<0, 1><<<GGRID, 256, 0, stream>>>(row, col16, dis, Hb, b1, Bb,
                                                nullptr, nullptr, k1a, k1b);

    // ---- layer 2 GEMM (dis-prescaled) + gather with fused classifier ----
    k_gemm_bf16<<<(N_NODES + 127) / 128, 256, 0, stream>>>(Bb, W2t, dis, Hb);
    k_gather_t<1, 0><<<GGRID, 256, 0, stream>>>(row, col16, dis, Hb, b2, nullptr,
                                                W3, h3s, k2a, k2b);

    // ---- layer 3 aggregate + log_softmax ----
    k_gather3<<<(N_NODES + 255) / 256, 256, 0, stream>>>(row, col16, dis, h3s, b3, out);
}